// Round 1
// baseline (542.321 us; speedup 1.0000x reference)
//
#include <hip/hip_runtime.h>
#include <hip/hip_bf16.h>
#include <math.h>

#define B_ 4
#define S_ 2048
#define C_ 1024
#define H_ 16
#define D_ 64
#define M_ (B_*S_)      // 8192
#define NQKV (3*C_)     // 3072
#define KDIM C_         // 1024

typedef float f32x4 __attribute__((ext_vector_type(4)));
typedef short bf16x8 __attribute__((ext_vector_type(8)));

static __device__ __forceinline__ ushort f2bf(float f){
    union { float f; unsigned int i; } v; v.f = f;
    unsigned int r = v.i + 0x7fffu + ((v.i >> 16) & 1u);
    return (ushort)(r >> 16);
}

// ---------------- convert x -> bf16 ----------------
__global__ void k_conv(const float* __restrict__ in, ushort* __restrict__ out, int n4){
    int i = blockIdx.x*blockDim.x + threadIdx.x;
    if (i < n4){
        float4 v = *(const float4*)(in + i*4);
        ushort4 o;
        o.x = f2bf(v.x); o.y = f2bf(v.y); o.z = f2bf(v.z); o.w = f2bf(v.w);
        *(ushort4*)(out + i*4) = o;
    }
}

// ---------------- transpose+convert W [R][Ccol] -> [Ccol][R] bf16 ----------------
__global__ void k_transpose(const float* __restrict__ in, ushort* __restrict__ out,
                            int R, int Ccol){
    __shared__ float tile[32][33];
    int c0 = blockIdx.x*32, r0 = blockIdx.y*32;
    int tx = threadIdx.x, ty = threadIdx.y;   // block (32,8)
    for (int j = ty; j < 32; j += 8)
        tile[j][tx] = in[(r0 + j)*Ccol + c0 + tx];
    __syncthreads();
    for (int j = ty; j < 32; j += 8)
        out[(size_t)(c0 + tx)*R + r0 + j] = f2bf(tile[j][tx]);
}

// ---------------- rope cos/sin tables [S][64] ----------------
__global__ void k_rope_tab(float* __restrict__ cosT, float* __restrict__ sinT){
    int t = blockIdx.x*blockDim.x + threadIdx.x;
    if (t >= S_*D_) return;
    int pos = t >> 6, j = t & 63;
    float invf = powf(10000.0f, -(float)(j & 31) / 32.0f);
    float ang = (float)pos * invf;
    cosT[t] = cosf(ang);
    sinT[t] = sinf(ang);
}

// ---------------- QKV GEMM + bias + RoPE + scatter to [B,H,S,D] ----------------
__launch_bounds__(256)
__global__ void k_qkv(const ushort* __restrict__ xb, const ushort* __restrict__ wt,
                      const float* __restrict__ bqkv,
                      const float* __restrict__ cosT, const float* __restrict__ sinT,
                      ushort* __restrict__ qb, ushort* __restrict__ kb, ushort* __restrict__ vb){
    __shared__ __align__(16) ushort As[64][32];
    __shared__ __align__(16) ushort Bs[64][32];
    int M0 = blockIdx.y*64, N0 = blockIdx.x*64;
    int tid = threadIdx.x;
    int wid = tid >> 6, lane = tid & 63;
    int wm = wid >> 1, wn = wid & 1;
    int lrow = lane & 15, lk = lane >> 4;

    f32x4 acc[2][2] = {};
    int r = tid >> 2, cg = tid & 3;
    for (int k0 = 0; k0 < KDIM; k0 += 32){
        *(int4*)(&As[r][cg*8]) = *(const int4*)(&xb[(M0 + r)*KDIM + k0 + cg*8]);
        *(int4*)(&Bs[r][cg*8]) = *(const int4*)(&wt[(N0 + r)*KDIM + k0 + cg*8]);
        __syncthreads();
        bf16x8 a[2], b[2];
#pragma unroll
        for (int mi = 0; mi < 2; mi++) a[mi] = *(const bf16x8*)(&As[wm*32 + mi*16 + lrow][lk*8]);
#pragma unroll
        for (int ni = 0; ni < 2; ni++) b[ni] = *(const bf16x8*)(&Bs[wn*32 + ni*16 + lrow][lk*8]);
#pragma unroll
        for (int mi = 0; mi < 2; mi++)
#pragma unroll
            for (int ni = 0; ni < 2; ni++)
                acc[mi][ni] = __builtin_amdgcn_mfma_f32_16x16x32_bf16(a[mi], b[ni], acc[mi][ni], 0, 0, 0);
        __syncthreads();
    }
#pragma unroll
    for (int mi = 0; mi < 2; mi++)
#pragma unroll
    for (int ni = 0; ni < 2; ni++){
        int gn = N0 + wn*32 + ni*16 + lrow;
        float bias = bqkv[gn];
        int which = gn >> 10;       // 0=q 1=k 2=v (uniform per block)
        int cn = gn & 1023;
        int h = cn >> 6, d = cn & 63;
#pragma unroll
        for (int rr = 0; rr < 4; rr++){
            int gm = M0 + wm*32 + mi*16 + lk*4 + rr;
            float val = acc[mi][ni][rr] + bias;
            float rot = __shfl_xor(val, 1);       // partner col (d^1), bias included
            int b = gm >> 11, pos = gm & 2047;
            int out_idx = (((b*H_ + h)*S_) + pos)*D_ + d;
            if (which == 2){
                vb[out_idx] = f2bf(val);
            } else {
                float c = cosT[pos*64 + d], s = sinT[pos*64 + d];
                float o = val*c + ((d & 1) ? rot : -rot)*s;
                ((which == 0) ? qb : kb)[out_idx] = f2bf(o);
            }
        }
    }
}

// ---------------- causal flash attention, [B,H,S,D] -> [B,S,C] bf16 ----------------
__launch_bounds__(256)
__global__ void k_attn(const ushort* __restrict__ qb, const ushort* __restrict__ kb,
                       const ushort* __restrict__ vb, ushort* __restrict__ ob){
    __shared__ __align__(16) ushort ptile[4][16][32];
    int bh = blockIdx.y;
    int b = bh >> 4, h = bh & 15;
    int tid = threadIdx.x, wid = tid >> 6, lane = tid & 63;
    int lrow = lane & 15, lk = lane >> 4;
    const ushort* qp = qb + bh*S_*D_;
    const ushort* kp = kb + bh*S_*D_;
    const ushort* vp = vb + bh*S_*D_;
    int qbase = blockIdx.x*64 + wid*16;

    bf16x8 fq[2];
#pragma unroll
    for (int kt = 0; kt < 2; kt++)
        fq[kt] = *(const bf16x8*)(&qp[(qbase + lrow)*D_ + kt*32 + lk*8]);

    f32x4 acc[4] = {};
    float mrun[4], lrun[4];
#pragma unroll
    for (int rr = 0; rr < 4; rr++){ mrun[rr] = -1e30f; lrun[rr] = 0.0f; }

    int kend = qbase + 16;      // need keys <= qbase+15
    for (int j0 = 0; j0 < kend; j0 += 32){
        bf16x8 fk[2][2];
#pragma unroll
        for (int s2 = 0; s2 < 2; s2++)
#pragma unroll
            for (int kt = 0; kt < 2; kt++)
                fk[s2][kt] = *(const bf16x8*)(&kp[(j0 + s2*16 + lrow)*D_ + kt*32 + lk*8]);
        f32x4 sc[2];
#pragma unroll
        for (int s2 = 0; s2 < 2; s2++){
            f32x4 z = {};
            z = __builtin_amdgcn_mfma_f32_16x16x32_bf16(fq[0], fk[s2][0], z, 0, 0, 0);
            z = __builtin_amdgcn_mfma_f32_16x16x32_bf16(fq[1], fk[s2][1], z, 0, 0, 0);
            sc[s2] = z;
        }
        float pv[2][4];
#pragma unroll
        for (int rr = 0; rr < 4; rr++){
            int qrow = qbase + lk*4 + rr;
            float v0[2];
#pragma unroll
            for (int s2 = 0; s2 < 2; s2++){
                int key = j0 + s2*16 + lrow;
                float scv = sc[s2][rr]*0.125f;
                if (key > qrow) scv = -1e30f;
                v0[s2] = scv;
            }
            float tmax = fmaxf(v0[0], v0[1]);
#pragma unroll
            for (int off = 1; off < 16; off <<= 1) tmax = fmaxf(tmax, __shfl_xor(tmax, off));
            float newm = fmaxf(mrun[rr], tmax);
            float resc = __expf(mrun[rr] - newm);
            float rsum = 0.0f;
#pragma unroll
            for (int s2 = 0; s2 < 2; s2++){
                float p = __expf(v0[s2] - newm);
                pv[s2][rr] = p;
                rsum += p;
            }
#pragma unroll
            for (int off = 1; off < 16; off <<= 1) rsum += __shfl_xor(rsum, off);
            lrun[rr] = lrun[rr]*resc + rsum;
            mrun[rr] = newm;
#pragma unroll
            for (int nt = 0; nt < 4; nt++) acc[nt][rr] *= resc;
        }
        // transpose P through per-wave LDS tile
#pragma unroll
        for (int s2 = 0; s2 < 2; s2++)
#pragma unroll
            for (int rr = 0; rr < 4; rr++)
                ptile[wid][lk*4 + rr][s2*16 + lrow] = f2bf(pv[s2][rr]);
        bf16x8 fp = *(const bf16x8*)(&ptile[wid][lrow][lk*8]);
#pragma unroll
        for (int nt = 0; nt < 4; nt++){
            bf16x8 fv;
#pragma unroll
            for (int e = 0; e < 8; e++)
                fv[e] = (short)vp[(j0 + lk*8 + e)*D_ + nt*16 + lrow];
            acc[nt] = __builtin_amdgcn_mfma_f32_16x16x32_bf16(fp, fv, acc[nt], 0, 0, 0);
        }
    }
#pragma unroll
    for (int nt = 0; nt < 4; nt++)
#pragma unroll
        for (int rr = 0; rr < 4; rr++){
            int qrow = qbase + lk*4 + rr;
            float o = acc[nt][rr] / lrun[rr];
            ob[(b*S_ + qrow)*C_ + h*D_ + nt*16 + lrow] = f2bf(o);
        }
}

// ---------------- proj GEMM + bias -> fp32 out ----------------
__launch_bounds__(256)
__global__ void k_proj(const ushort* __restrict__ ab, const ushort* __restrict__ wt,
                       const float* __restrict__ bias, float* __restrict__ out){
    __shared__ __align__(16) ushort As[64][32];
    __shared__ __align__(16) ushort Bs[64][32];
    int M0 = blockIdx.y*64, N0 = blockIdx.x*64;
    int tid = threadIdx.x;
    int wid = tid >> 6, lane = tid & 63;
    int wm = wid >> 1, wn = wid & 1;
    int lrow = lane & 15, lk = lane >> 4;

    f32x4 acc[2][2] = {};
    int r = tid >> 2, cg = tid & 3;
    for (int k0 = 0; k0 < KDIM; k0 += 32){
        *(int4*)(&As[r][cg*8]) = *(const int4*)(&ab[(M0 + r)*KDIM + k0 + cg*8]);
        *(int4*)(&Bs[r][cg*8]) = *(const int4*)(&wt[(N0 + r)*KDIM + k0 + cg*8]);
        __syncthreads();
        bf16x8 a[2], b[2];
#pragma unroll
        for (int mi = 0; mi < 2; mi++) a[mi] = *(const bf16x8*)(&As[wm*32 + mi*16 + lrow][lk*8]);
#pragma unroll
        for (int ni = 0; ni < 2; ni++) b[ni] = *(const bf16x8*)(&Bs[wn*32 + ni*16 + lrow][lk*8]);
#pragma unroll
        for (int mi = 0; mi < 2; mi++)
#pragma unroll
            for (int ni = 0; ni < 2; ni++)
                acc[mi][ni] = __builtin_amdgcn_mfma_f32_16x16x32_bf16(a[mi], b[ni], acc[mi][ni], 0, 0, 0);
        __syncthreads();
    }
#pragma unroll
    for (int mi = 0; mi < 2; mi++)
#pragma unroll
    for (int ni = 0; ni < 2; ni++){
        int gn = N0 + wn*32 + ni*16 + lrow;
        float bv = bias[gn];
#pragma unroll
        for (int rr = 0; rr < 4; rr++){
            int gm = M0 + wm*32 + mi*16 + lk*4 + rr;
            out[gm*C_ + gn] = acc[mi][ni][rr] + bv;
        }
    }
}

extern "C" void kernel_launch(void* const* d_in, const int* in_sizes, int n_in,
                              void* d_out, int out_size, void* d_ws, size_t ws_size,
                              hipStream_t stream) {
    const float* x     = (const float*)d_in[0];
    const float* Wqkv  = (const float*)d_in[1];
    const float* bqkv  = (const float*)d_in[2];
    const float* Wproj = (const float*)d_in[3];
    const float* bproj = (const float*)d_in[4];
    float* out = (float*)d_out;

    char* ws = (char*)d_ws;
    ushort* xb   = (ushort*)(ws);                                  // 16 MB
    ushort* wqt  = (ushort*)(ws + (16u<<20));                      // 6 MB
    ushort* wpt  = (ushort*)(ws + (22u<<20));                      // 2 MB
    float*  cosT = (float*) (ws + (24u<<20));                      // 0.5 MB
    float*  sinT = (float*) (ws + (24u<<20) + (512u<<10));         // 0.5 MB
    ushort* qbuf = (ushort*)(ws + (25u<<20));                      // 16 MB
    ushort* kbuf = (ushort*)(ws + (41u<<20));                      // 16 MB
    ushort* vbuf = (ushort*)(ws + (57u<<20));                      // 16 MB
    ushort* obuf = (ushort*)(ws + (73u<<20));                      // 16 MB

    k_conv<<<(M_*KDIM/4 + 255)/256, 256, 0, stream>>>(x, xb, M_*KDIM/4);
    dim3 tb(32, 8);
    k_transpose<<<dim3(NQKV/32, KDIM/32), tb, 0, stream>>>(Wqkv, wqt, KDIM, NQKV);
    k_transpose<<<dim3(C_/32, KDIM/32), tb, 0, stream>>>(Wproj, wpt, KDIM, C_);
    k_rope_tab<<<(S_*D_ + 255)/256, 256, 0, stream>>>(cosT, sinT);

    k_qkv<<<dim3(NQKV/64, M_/64), 256, 0, stream>>>(xb, wqt, bqkv, cosT, sinT, qbuf, kbuf, vbuf);
    k_attn<<<dim3(S_/64, B_*H_), 256, 0, stream>>>(qbuf, kbuf, vbuf, obuf);
    k_proj<<<dim3(C_/64, M_/64), 256, 0, stream>>>(obuf, wpt, bproj, out);
}